// Round 7
// baseline (253.762 us; speedup 1.0000x reference)
//
#include <hip/hip_runtime.h>
#include <hip/hip_bf16.h>
#include <math.h>

#define N_Q 2048
#define M_K 1024
#define DIN 128
#define DK  64
#define NBLK 256
#define MAGIC 0x5EEDC0DEu

typedef __attribute__((ext_vector_type(8))) short short8;
typedef __attribute__((ext_vector_type(4))) float f32x4;
typedef __attribute__((ext_vector_type(4))) unsigned int u32x4;

// bf16 hi/lo split of an fp32 value, packed into one dword (hi in low 16)
static __device__ __forceinline__ unsigned int pack_split(float v)
{
    __hip_bfloat16 hb = __float2bfloat16(v);
    float hf = __bfloat162float(hb);
    __hip_bfloat16 lb = __float2bfloat16(v - hf);
    return (unsigned int)(*(unsigned short*)&hb)
         | ((unsigned int)(*(unsigned short*)&lb) << 16);
}

// unpack 8 packed u32 (8 k-elems) -> hi short8 + lo short8 (bf16 bit patterns)
static __device__ __forceinline__ void unpack8(const unsigned int* p,
                                               short8& h, short8& l)
{
    u32x4 a = *(const u32x4*)p;
    u32x4 b = *(const u32x4*)(p + 4);
    u32x4 hu, lu;
    hu.x = (a.x & 0xFFFFu) | (a.y << 16);
    hu.y = (a.z & 0xFFFFu) | (a.w << 16);
    hu.z = (b.x & 0xFFFFu) | (b.y << 16);
    hu.w = (b.z & 0xFFFFu) | (b.w << 16);
    lu.x = (a.x >> 16) | (a.y & 0xFFFF0000u);
    lu.y = (a.z >> 16) | (a.w & 0xFFFF0000u);
    lu.z = (b.x >> 16) | (b.y & 0xFFFF0000u);
    lu.w = (b.z >> 16) | (b.w & 0xFFFF0000u);
    union { u32x4 u; short8 s; } ch, cl;
    ch.u = hu; cl.u = lu;
    h = ch.s; l = cl.s;
}

// wave-uniform spin on a producer flag (all 64 lanes same address -> 1 req)
static __device__ __forceinline__ void wait_flag(const unsigned int* f)
{
    while (__hip_atomic_load(f, __ATOMIC_ACQUIRE, __HIP_MEMORY_SCOPE_AGENT)
           != MAGIC)
        __builtin_amdgcn_s_sleep(2);
}

// ---------------------------------------------------------------------------
// ONE kernel node, no barrier, no memset. 256 blocks x 1024 thr (16 waves,
// 4 waves/SIMD at 1 block/CU; 45 KB LDS).
// Proj: waves 0-7 -> q-rows bid*8..+7 (packed split + qn2 kept in LDS);
//       waves 8-15 (bid<128) -> k-rows bid*8..+7 to global Khl/kn2, then
//       tx0 release-stores flag[bid]=MAGIC after __syncthreads drain.
// Sync: consumer waves poll only the 2 flags covering their next 16-row
//       tile (128 distinct lines -> no hot-line contention). MAGIC sentinel
//       makes replays with stale ws correct AND fast (deterministic values).
// Score: R5-validated split-bf16 MFMA (hh+hl+lh), wave strip = 64 cols
//       (4 tiles of 16x16, A-rows duplicated via c&7), fused softmax
//       epilogue across 16 waves.
// ---------------------------------------------------------------------------
__global__ __launch_bounds__(1024, 4) void fused_kernel(
    const float* __restrict__ q, const float* __restrict__ k,
    const float* __restrict__ W,
    unsigned int* __restrict__ Khl, float* __restrict__ kn2,
    unsigned int* __restrict__ flags, float* __restrict__ out)
{
    __shared__ float W_lds[DK][DIN + 4];      // 33.8 KB, stride 132 (b128 ok)
    __shared__ float row_lds[16][DIN];        // 8 KB
    __shared__ unsigned int qhl[8][68];       // 2.2 KB packed Q split, 16B rows
    __shared__ float qn2s[8];
    __shared__ float redmax[8][16];
    __shared__ float redsum[8][16];

    const int tx = threadIdx.x;
    const int w = tx >> 6, lane = tx & 63;
    const int bid = blockIdx.x;

    // ---- stage W: 2048 float4s over 1024 threads ----
    const float4* W4 = (const float4*)W;
    #pragma unroll
    for (int i = 0; i < 2; ++i) {
        int idx = tx + i * 1024;
        float4 v = W4[idx];
        *(float4*)&W_lds[idx >> 5][(idx & 31) * 4] = v;
    }

    // ---- stage this wave's input row ----
    const bool pactive = (w < 8) || (bid < 128);
    {
        const float* src = (w < 8) ? (q + ((size_t)bid * 8 + w) * DIN)
                   : (bid < 128) ? (k + ((size_t)bid * 8 + (w - 8)) * DIN)
                                 : (const float*)0;
        if (src) {
            row_lds[w][lane]      = src[lane];
            row_lds[w][lane + 64] = src[lane + 64];
        }
    }
    __syncthreads();

    // ---- projection dot: lane = output dim (R2-proven pattern) ----
    if (pactive) {
        float acc = 0.f;
        #pragma unroll
        for (int d = 0; d < DIN; d += 4) {
            float4 wv = *(const float4*)&W_lds[lane][d];
            float4 rv = *(const float4*)&row_lds[w][d];
            acc = fmaf(wv.x, rv.x, acc);
            acc = fmaf(wv.y, rv.y, acc);
            acc = fmaf(wv.z, rv.z, acc);
            acc = fmaf(wv.w, rv.w, acc);
        }
        float sq = acc * acc;
        #pragma unroll
        for (int off = 32; off >= 1; off >>= 1) sq += __shfl_xor(sq, off, 64);
        unsigned int packed = pack_split(acc);

        if (w < 8) {
            qhl[w][lane] = packed;
            if (lane == 0) qn2s[w] = sq;
        } else {
            const int krow = bid * 8 + (w - 8);
            Khl[(size_t)krow * DK + lane] = packed;
            if (lane == 0) kn2[krow] = sq;
        }
    }
    __syncthreads();   // qhl/qn2s visible; all waves' global stores drained

    if (bid < 128 && tx == 0)
        __hip_atomic_store(&flags[bid], MAGIC, __ATOMIC_RELEASE,
                           __HIP_MEMORY_SCOPE_AGENT);

    // ---- score phase ----
    const int g = lane >> 4, c = lane & 15;
    const int n0 = bid * 8;

    short8 Ah0, Al0, Ah1, Al1;
    unpack8(&qhl[c & 7][g * 8],      Ah0, Al0);
    unpack8(&qhl[c & 7][32 + g * 8], Ah1, Al1);

    float qn[4];
    #pragma unroll
    for (int j = 0; j < 4; ++j) qn[j] = qn2s[(4 * g + j) & 7];

    float s[4][4];
    #pragma unroll
    for (int t = 0; t < 4; ++t) {
        const int m0 = w * 64 + t * 16;         // tile base col (m)
        wait_flag(&flags[m0 >> 3]);             // producers of rows m0..m0+7
        wait_flag(&flags[(m0 >> 3) + 1]);       // and m0+8..m0+15
        const int m = m0 + c;
        const unsigned int* kr = Khl + (size_t)m * DK;
        short8 Bh0, Bl0, Bh1, Bl1;
        unpack8(kr + g * 8, Bh0, Bl0);
        unpack8(kr + 32 + g * 8, Bh1, Bl1);

        f32x4 a4 = {0.f, 0.f, 0.f, 0.f};
        a4 = __builtin_amdgcn_mfma_f32_16x16x32_bf16(Ah0, Bh0, a4, 0, 0, 0);
        a4 = __builtin_amdgcn_mfma_f32_16x16x32_bf16(Ah1, Bh1, a4, 0, 0, 0);
        a4 = __builtin_amdgcn_mfma_f32_16x16x32_bf16(Ah0, Bl0, a4, 0, 0, 0);
        a4 = __builtin_amdgcn_mfma_f32_16x16x32_bf16(Ah1, Bl1, a4, 0, 0, 0);
        a4 = __builtin_amdgcn_mfma_f32_16x16x32_bf16(Al0, Bh0, a4, 0, 0, 0);
        a4 = __builtin_amdgcn_mfma_f32_16x16x32_bf16(Al1, Bh1, a4, 0, 0, 0);

        const float kn = kn2[m];
        #pragma unroll
        for (int j = 0; j < 4; ++j) {
            float d2 = fmaxf(qn[j] + kn - 2.f * a4[j], 0.f);
            s[t][j] = -0.5f * sqrtf(d2);
        }
    }

    // ---- fused softmax epilogue (rows 0-7; g>=2 lanes are duplicates) ----
    #pragma unroll
    for (int j = 0; j < 4; ++j) {
        float m4 = fmaxf(fmaxf(s[0][j], s[1][j]), fmaxf(s[2][j], s[3][j]));
        m4 = fmaxf(m4, __shfl_xor(m4, 1, 64));
        m4 = fmaxf(m4, __shfl_xor(m4, 2, 64));
        m4 = fmaxf(m4, __shfl_xor(m4, 4, 64));
        m4 = fmaxf(m4, __shfl_xor(m4, 8, 64));
        if (c == 0 && g < 2) redmax[4 * g + j][w] = m4;
    }
    __syncthreads();

    float mx[4];
    #pragma unroll
    for (int j = 0; j < 4; ++j) {
        const float* rm = redmax[(4 * g + j) & 7];
        float m = rm[0];
        #pragma unroll
        for (int ww = 1; ww < 16; ++ww) m = fmaxf(m, rm[ww]);
        mx[j] = m;
    }

    #pragma unroll
    for (int j = 0; j < 4; ++j) {
        float t4 = 0.f;
        #pragma unroll
        for (int t = 0; t < 4; ++t) {
            s[t][j] = __expf(s[t][j] - mx[j]);
            t4 += s[t][j];
        }
        t4 += __shfl_xor(t4, 1, 64);
        t4 += __shfl_xor(t4, 2, 64);
        t4 += __shfl_xor(t4, 4, 64);
        t4 += __shfl_xor(t4, 8, 64);
        if (c == 0 && g < 2) redsum[4 * g + j][w] = t4;
    }
    __syncthreads();

    if (g < 2) {
        float inv[4];
        #pragma unroll
        for (int j = 0; j < 4; ++j) {
            const float* rs = redsum[4 * g + j];
            float t = 0.f;
            #pragma unroll
            for (int ww = 0; ww < 16; ++ww) t += rs[ww];
            inv[j] = 1.0f / t;
        }
        #pragma unroll
        for (int t = 0; t < 4; ++t) {
            const int m = w * 64 + t * 16 + c;
            #pragma unroll
            for (int j = 0; j < 4; ++j)
                out[(size_t)(n0 + 4 * g + j) * M_K + m] = s[t][j] * inv[j];
        }
    }
}

extern "C" void kernel_launch(void* const* d_in, const int* in_sizes, int n_in,
                              void* d_out, int out_size, void* d_ws, size_t ws_size,
                              hipStream_t stream)
{
    const float* q = (const float*)d_in[0];
    const float* k = (const float*)d_in[1];
    const float* W = (const float*)d_in[2];
    float* out = (float*)d_out;

    // ws layout (bytes): Khl 256K @0 | kn2 4K @262144 | flags 512B @266240
    unsigned char* base = (unsigned char*)d_ws;
    unsigned int* Khl = (unsigned int*)base;
    float* kn2 = (float*)(base + 262144);
    unsigned int* flags = (unsigned int*)(base + 266240);

    fused_kernel<<<NBLK, 1024, 0, stream>>>(q, k, W, Khl, kn2, flags, out);
}

// Round 8
// 25.158 us; speedup vs baseline: 10.0869x; 10.0869x over previous
//
#include <hip/hip_runtime.h>
#include <hip/hip_bf16.h>
#include <math.h>

#define N_Q 2048
#define M_K 1024
#define DIN 128
#define DK  64

typedef __attribute__((ext_vector_type(8))) short short8;
typedef __attribute__((ext_vector_type(4))) float f32x4;
typedef __attribute__((ext_vector_type(4))) unsigned int u32x4;

// bf16 hi/lo split of an fp32 value, packed into one dword (hi in low 16)
static __device__ __forceinline__ unsigned int pack_split(float v)
{
    __hip_bfloat16 hb = __float2bfloat16(v);
    float hf = __bfloat162float(hb);
    __hip_bfloat16 lb = __float2bfloat16(v - hf);
    return (unsigned int)(*(unsigned short*)&hb)
         | ((unsigned int)(*(unsigned short*)&lb) << 16);
}

// unpack 8 packed u32 (8 k-elems) -> hi short8 + lo short8 (bf16 bit patterns)
static __device__ __forceinline__ void unpack8(const unsigned int* p,
                                               short8& h, short8& l)
{
    u32x4 a = *(const u32x4*)p;
    u32x4 b = *(const u32x4*)(p + 4);
    u32x4 hu, lu;
    hu.x = (a.x & 0xFFFFu) | (a.y << 16);
    hu.y = (a.z & 0xFFFFu) | (a.w << 16);
    hu.z = (b.x & 0xFFFFu) | (b.y << 16);
    hu.w = (b.z & 0xFFFFu) | (b.w << 16);
    lu.x = (a.x >> 16) | (a.y & 0xFFFF0000u);
    lu.y = (a.z >> 16) | (a.w & 0xFFFF0000u);
    lu.z = (b.x >> 16) | (b.y & 0xFFFF0000u);
    lu.w = (b.z >> 16) | (b.w & 0xFFFF0000u);
    union { u32x4 u; short8 s; } ch, cl;
    ch.u = hu; cl.u = lu;
    h = ch.s; l = cl.s;
}

// ---------------------------------------------------------------------------
// Kernel 1: 384 blocks x 512 thr (8 waves), one row per wave (rows 0..3071:
// q then k). W staged once per block (33 KB) amortized over 8 rows.
// Emits packed bf16 hi/lo split (one dword/elem, coalesced) + fp32 norms.
// ---------------------------------------------------------------------------
__global__ __launch_bounds__(512) void proj_kernel(
    const float* __restrict__ q, const float* __restrict__ k,
    const float* __restrict__ W,
    unsigned int* __restrict__ Qhl, unsigned int* __restrict__ Khl,
    float* __restrict__ qn2, float* __restrict__ kn2)
{
    __shared__ float W_lds[DK][DIN + 4];   // stride 132: b128 conflict-free
    __shared__ float row_lds[8][DIN];
    const int tx = threadIdx.x;
    const int w = tx >> 6, lane = tx & 63;

    // cooperative W stage: 2048 float4s, 4 per thread
    const float4* W4 = (const float4*)W;
    #pragma unroll
    for (int i = 0; i < 4; ++i) {
        int idx = tx + i * 512;
        float4 v = W4[idx];
        *(float4*)&W_lds[idx >> 5][(idx & 31) * 4] = v;
    }

    const int row = blockIdx.x * 8 + w;                // 0..3071
    const float* src = (row < N_Q) ? (q + (size_t)row * DIN)
                                   : (k + (size_t)(row - N_Q) * DIN);
    row_lds[w][lane]      = src[lane];
    row_lds[w][lane + 64] = src[lane + 64];
    __syncthreads();

    float acc = 0.f;                                   // lane = output dim
    #pragma unroll
    for (int d = 0; d < DIN; d += 4) {
        float4 wv = *(const float4*)&W_lds[lane][d];
        float4 rv = *(const float4*)&row_lds[w][d];
        acc = fmaf(wv.x, rv.x, acc);
        acc = fmaf(wv.y, rv.y, acc);
        acc = fmaf(wv.z, rv.z, acc);
        acc = fmaf(wv.w, rv.w, acc);
    }

    float sq = acc * acc;                              // exact fp32 norm
    #pragma unroll
    for (int off = 32; off >= 1; off >>= 1)
        sq += __shfl_xor(sq, off, 64);

    unsigned int packed = pack_split(acc);
    if (row < N_Q) {
        Qhl[(size_t)row * DK + lane] = packed;
        if (lane == 0) qn2[row] = sq;
    } else {
        const int m = row - N_Q;
        Khl[(size_t)m * DK + lane] = packed;
        if (lane == 0) kn2[m] = sq;
    }
}

// ---------------------------------------------------------------------------
// Kernel 2: 256 blocks x 512 thr (8 waves) -> full chip. Block = 8 q-rows x
// all 1024 m. Wave w owns cols [128w,128w+128): 8 tiles of 16x16 via
// mfma_f32_16x16x32_bf16, split-bf16 fp32 emulation (hh+hl+lh).
// A-frag rows duplicated via c&7 (validated R6); g<2 lane-groups own the
// 8 real rows for reductions/stores. Khl (256 KB) is L2-resident per XCD.
// C layout: col=lane&15 (m), row=4*(lane>>4)+reg (n)  [m89-verified].
// ---------------------------------------------------------------------------
__global__ __launch_bounds__(512) void score_kernel(
    const unsigned int* __restrict__ Qhl, const unsigned int* __restrict__ Khl,
    const float* __restrict__ qn2, const float* __restrict__ kn2,
    float* __restrict__ out)
{
    __shared__ float redmax[8][8];
    __shared__ float redsum[8][8];

    const int tx = threadIdx.x;
    const int w = tx >> 6, l = tx & 63;
    const int g = l >> 4, c = l & 15;
    const int n0 = blockIdx.x * 8;

    // A fragments: lane holds Q[n0+(c&7)][8g..8g+7] / +32
    const unsigned int* qr = Qhl + (size_t)(n0 + (c & 7)) * DK;
    short8 Ah0, Al0, Ah1, Al1;
    unpack8(qr + g * 8, Ah0, Al0);
    unpack8(qr + 32 + g * 8, Ah1, Al1);

    float qn[4];
    #pragma unroll
    for (int j = 0; j < 4; ++j) qn[j] = qn2[n0 + ((4 * g + j) & 7)];

    float s[8][4];
    #pragma unroll
    for (int t = 0; t < 8; ++t) {
        const int m = w * 128 + t * 16 + c;
        const unsigned int* kr = Khl + (size_t)m * DK;
        short8 Bh0, Bl0, Bh1, Bl1;
        unpack8(kr + g * 8, Bh0, Bl0);
        unpack8(kr + 32 + g * 8, Bh1, Bl1);

        f32x4 a4 = {0.f, 0.f, 0.f, 0.f};
        a4 = __builtin_amdgcn_mfma_f32_16x16x32_bf16(Ah0, Bh0, a4, 0, 0, 0);
        a4 = __builtin_amdgcn_mfma_f32_16x16x32_bf16(Ah1, Bh1, a4, 0, 0, 0);
        a4 = __builtin_amdgcn_mfma_f32_16x16x32_bf16(Ah0, Bl0, a4, 0, 0, 0);
        a4 = __builtin_amdgcn_mfma_f32_16x16x32_bf16(Ah1, Bl1, a4, 0, 0, 0);
        a4 = __builtin_amdgcn_mfma_f32_16x16x32_bf16(Al0, Bh0, a4, 0, 0, 0);
        a4 = __builtin_amdgcn_mfma_f32_16x16x32_bf16(Al1, Bh1, a4, 0, 0, 0);

        const float kn = kn2[m];
        #pragma unroll
        for (int j = 0; j < 4; ++j) {
            float d2 = fmaxf(qn[j] + kn - 2.f * a4[j], 0.f);
            s[t][j] = -0.5f * sqrtf(d2);
        }
    }

    // row max over this wave's 128 cols, then across 8 waves via LDS
    #pragma unroll
    for (int j = 0; j < 4; ++j) {
        float m8 = s[0][j];
        #pragma unroll
        for (int t = 1; t < 8; ++t) m8 = fmaxf(m8, s[t][j]);
        m8 = fmaxf(m8, __shfl_xor(m8, 1, 64));
        m8 = fmaxf(m8, __shfl_xor(m8, 2, 64));
        m8 = fmaxf(m8, __shfl_xor(m8, 4, 64));
        m8 = fmaxf(m8, __shfl_xor(m8, 8, 64));
        if (c == 0 && g < 2) redmax[4 * g + j][w] = m8;
    }
    __syncthreads();

    float mx[4];
    #pragma unroll
    for (int j = 0; j < 4; ++j) {
        const float* rm = redmax[(4 * g + j) & 7];
        float m = rm[0];
        #pragma unroll
        for (int ww = 1; ww < 8; ++ww) m = fmaxf(m, rm[ww]);
        mx[j] = m;
    }

    // exp + row sum
    #pragma unroll
    for (int j = 0; j < 4; ++j) {
        float t8 = 0.f;
        #pragma unroll
        for (int t = 0; t < 8; ++t) {
            s[t][j] = __expf(s[t][j] - mx[j]);
            t8 += s[t][j];
        }
        t8 += __shfl_xor(t8, 1, 64);
        t8 += __shfl_xor(t8, 2, 64);
        t8 += __shfl_xor(t8, 4, 64);
        t8 += __shfl_xor(t8, 8, 64);
        if (c == 0 && g < 2) redsum[4 * g + j][w] = t8;
    }
    __syncthreads();

    if (g < 2) {
        float inv[4];
        #pragma unroll
        for (int j = 0; j < 4; ++j) {
            const float* rs = redsum[4 * g + j];
            float t = 0.f;
            #pragma unroll
            for (int ww = 0; ww < 8; ++ww) t += rs[ww];
            inv[j] = 1.0f / t;
        }
        #pragma unroll
        for (int t = 0; t < 8; ++t) {
            const int m = w * 128 + t * 16 + c;
            #pragma unroll
            for (int j = 0; j < 4; ++j)
                out[(size_t)(n0 + 4 * g + j) * M_K + m] = s[t][j] * inv[j];
        }
    }
}

extern "C" void kernel_launch(void* const* d_in, const int* in_sizes, int n_in,
                              void* d_out, int out_size, void* d_ws, size_t ws_size,
                              hipStream_t stream)
{
    const float* q = (const float*)d_in[0];
    const float* k = (const float*)d_in[1];
    const float* W = (const float*)d_in[2];
    float* out = (float*)d_out;

    // ws layout (bytes): Qhl 512K | Khl 256K | qn2 8K | kn2 4K
    unsigned char* base = (unsigned char*)d_ws;
    unsigned int* Qhl = (unsigned int*)base;
    unsigned int* Khl = (unsigned int*)(base + 524288);
    float* qn2 = (float*)(base + 786432);
    float* kn2 = (float*)(base + 794624);

    proj_kernel<<<(N_Q + M_K) / 8, 512, 0, stream>>>(q, k, W, Qhl, Khl, qn2, kn2);
    score_kernel<<<N_Q / 8, 512, 0, stream>>>(Qhl, Khl, qn2, kn2, out);
}